// Round 1
// baseline (1237.819 us; speedup 1.0000x reference)
//
#include <hip/hip_runtime.h>
#include <stdint.h>
#include <stddef.h>

typedef __attribute__((ext_vector_type(8))) short short8;
typedef __attribute__((ext_vector_type(4))) float f32x4;
typedef unsigned short u16;

#define B_ 4
#define S_ 2048
#define H_ 2048
#define I_ 5504
#define M_ 8192  // B*S

__device__ __forceinline__ u16 f2bf(float f) {
  uint32_t u = __float_as_uint(f);
  u += 0x7fff + ((u >> 16) & 1);   // round-to-nearest-even
  return (u16)(u >> 16);
}

#define GLOAD_LDS16(src, dst)                                                              \
  __builtin_amdgcn_global_load_lds((const __attribute__((address_space(1))) void*)(src),   \
                                   (__attribute__((address_space(3))) void*)(dst), 16, 0, 0)

// Stage a 128x64 bf16 tile (16 KiB) from global (row stride ldE elements) into linear LDS.
// global_load_lds semantics: LDS dest = wave-uniform base + lane*16 (m104/m108).
__device__ __forceinline__ void stage128x64(const u16* g0, int ldE, u16* lds, int tid) {
  const int lane = tid & 63;
  const int w = tid >> 6;
  const char* gb = (const char*)g0;
  char* lb = (char*)lds;
#pragma unroll
  for (int t = 0; t < 4; ++t) {
    const int flat = w * 1024 + t * 4096 + lane * 16;  // byte offset in 16KiB tile
    const int row = flat >> 7;                         // 128 B per row (64 bf16)
    const int colb = flat & 127;
    GLOAD_LDS16(gb + (size_t)row * (ldE * 2) + colb, lb + w * 1024 + t * 4096);
  }
}

// ---------------- fp32 -> bf16 convert (vectorized) ----------------
__global__ __launch_bounds__(256) void cvt_f32_bf16(const float* __restrict__ in,
                                                    u16* __restrict__ out, int n4) {
  int i = blockIdx.x * 256 + threadIdx.x;
  if (i < n4) {
    float4 v = ((const float4*)in)[i];
    ushort4 o;
    o.x = f2bf(v.x);
    o.y = f2bf(v.y);
    o.z = f2bf(v.z);
    o.w = f2bf(v.w);
    ((ushort4*)out)[i] = o;
  }
}

// ---------------- fused gate/up GEMM + SwiGLU + s-reduction ----------------
// inter[m,i] = silu(X@Wg^T) * (X@Wu^T);  s[b,i] += sum_rows inter^2
__global__ __launch_bounds__(256) void gemm_gateup(const u16* __restrict__ X,    // [8192,2048]
                                                   const u16* __restrict__ Wg,   // [5504,2048]
                                                   const u16* __restrict__ Wu,   // [5504,2048]
                                                   u16* __restrict__ inter,      // [8192,5504]
                                                   float* __restrict__ s) {      // [4,5504]
  const int NT = I_ / 128;  // 43
  // XCD-aware swizzle (grid 2752 = 8*344, divisible by 8 -> simple form valid)
  const int nwg = gridDim.x;
  const int cpx = nwg >> 3;
  const int swz = (blockIdx.x & 7) * cpx + (blockIdx.x >> 3);
  const int mt = swz / NT;
  const int nt = swz % NT;

  __shared__ __align__(16) u16 As[128 * 64];
  __shared__ __align__(16) u16 Bg[128 * 64];
  __shared__ __align__(16) u16 Bu[128 * 64];
  __shared__ float s_tile[128];

  const int tid = threadIdx.x;
  const int lane = tid & 63;
  const int wid = tid >> 6;
  const int wr = wid >> 1;  // 0..1
  const int wc = wid & 1;   // 0..1
  if (tid < 128) s_tile[tid] = 0.f;

  f32x4 accg[4][4] = {};
  f32x4 accu[4][4] = {};

  const u16* Xt = X + (size_t)(mt * 128) * H_;
  const u16* Wgt = Wg + (size_t)(nt * 128) * H_;
  const u16* Wut = Wu + (size_t)(nt * 128) * H_;

  const int l15 = lane & 15;
  const int kq = (lane >> 4) * 8;      // k sub-offset within 32
  const int arow = wr * 64 + l15;      // + m*16
  const int brow = wc * 64 + l15;      // + n*16

#pragma unroll 1
  for (int kt = 0; kt < H_; kt += 64) {
    __syncthreads();  // previous tile fully consumed
    stage128x64(Xt + kt, H_, As, tid);
    stage128x64(Wgt + kt, H_, Bg, tid);
    stage128x64(Wut + kt, H_, Bu, tid);
    __syncthreads();  // staging drained (vmcnt(0) before barrier)
#pragma unroll
    for (int ks = 0; ks < 2; ++ks) {
      const int ko = ks * 32 + kq;
      short8 a[4], bg[4], bu[4];
#pragma unroll
      for (int m = 0; m < 4; ++m) a[m] = *(const short8*)(As + (arow + m * 16) * 64 + ko);
#pragma unroll
      for (int n = 0; n < 4; ++n) {
        bg[n] = *(const short8*)(Bg + (brow + n * 16) * 64 + ko);
        bu[n] = *(const short8*)(Bu + (brow + n * 16) * 64 + ko);
      }
#pragma unroll
      for (int m = 0; m < 4; ++m)
#pragma unroll
        for (int n = 0; n < 4; ++n) {
          accg[m][n] = __builtin_amdgcn_mfma_f32_16x16x32_bf16(a[m], bg[n], accg[m][n], 0, 0, 0);
          accu[m][n] = __builtin_amdgcn_mfma_f32_16x16x32_bf16(a[m], bu[n], accu[m][n], 0, 0, 0);
        }
    }
  }

  // Epilogue: silu(g)*u, write bf16 inter, accumulate sum over rows of v^2 per column.
  // C/D layout (m89-verified): col = lane&15, row = (lane>>4)*4 + j  (within 16x16 frag)
  const int rb = mt * 128 + wr * 64 + (lane >> 4) * 4;
  const int cb = nt * 128 + wc * 64 + l15;
  float sp[4] = {0.f, 0.f, 0.f, 0.f};
#pragma unroll
  for (int m = 0; m < 4; ++m) {
#pragma unroll
    for (int n = 0; n < 4; ++n) {
#pragma unroll
      for (int j = 0; j < 4; ++j) {
        const float g = accg[m][n][j];
        const float u = accu[m][n][j];
        const float v = (g / (1.f + __expf(-g))) * u;  // silu(g)*u
        sp[n] += v * v;
        inter[(size_t)(rb + m * 16 + j) * I_ + (cb + n * 16)] = f2bf(v);
      }
    }
  }
#pragma unroll
  for (int n = 0; n < 4; ++n) atomicAdd(&s_tile[wc * 64 + n * 16 + l15], sp[n]);
  __syncthreads();
  if (tid < 128) {
    const int b = mt >> 4;  // 16 M-tiles per batch (2048/128)
    atomicAdd(&s[b * I_ + nt * 128 + tid], s_tile[tid]);
  }
}

// ---------------- down GEMM: out = inter @ w_down^T (fp32 out) ----------------
__global__ __launch_bounds__(256) void gemm_down(const u16* __restrict__ A,   // [8192,5504]
                                                 const u16* __restrict__ Wd,  // [2048,5504]
                                                 float* __restrict__ out) {   // [8192,2048]
  const int NT = H_ / 128;  // 16
  const int nwg = gridDim.x;
  const int cpx = nwg >> 3;
  const int swz = (blockIdx.x & 7) * cpx + (blockIdx.x >> 3);
  const int mt = swz / NT;
  const int nt = swz % NT;

  __shared__ __align__(16) u16 As[128 * 64];
  __shared__ __align__(16) u16 Bs[128 * 64];

  const int tid = threadIdx.x;
  const int lane = tid & 63;
  const int wid = tid >> 6;
  const int wr = wid >> 1;
  const int wc = wid & 1;

  f32x4 acc[4][4] = {};

  const u16* At = A + (size_t)(mt * 128) * I_;
  const u16* Bt = Wd + (size_t)(nt * 128) * I_;

  const int l15 = lane & 15;
  const int kq = (lane >> 4) * 8;
  const int arow = wr * 64 + l15;
  const int brow = wc * 64 + l15;

#pragma unroll 1
  for (int kt = 0; kt < I_; kt += 64) {  // 86 steps
    __syncthreads();
    stage128x64(At + kt, I_, As, tid);
    stage128x64(Bt + kt, I_, Bs, tid);
    __syncthreads();
#pragma unroll
    for (int ks = 0; ks < 2; ++ks) {
      const int ko = ks * 32 + kq;
      short8 a[4], b[4];
#pragma unroll
      for (int m = 0; m < 4; ++m) a[m] = *(const short8*)(As + (arow + m * 16) * 64 + ko);
#pragma unroll
      for (int n = 0; n < 4; ++n) b[n] = *(const short8*)(Bs + (brow + n * 16) * 64 + ko);
#pragma unroll
      for (int m = 0; m < 4; ++m)
#pragma unroll
        for (int n = 0; n < 4; ++n)
          acc[m][n] = __builtin_amdgcn_mfma_f32_16x16x32_bf16(a[m], b[n], acc[m][n], 0, 0, 0);
    }
  }

  const int rb = mt * 128 + wr * 64 + (lane >> 4) * 4;
  const int cb = nt * 128 + wc * 64 + l15;
#pragma unroll
  for (int m = 0; m < 4; ++m)
#pragma unroll
    for (int n = 0; n < 4; ++n)
#pragma unroll
      for (int j = 0; j < 4; ++j)
        out[(size_t)(rb + m * 16 + j) * H_ + (cb + n * 16)] = acc[m][n][j];
}

// ---------------- row_sq (fp32 w_up) + impacts ----------------
__global__ __launch_bounds__(256) void rowsq_impacts(const float* __restrict__ wu,  // [5504,2048] fp32
                                                     const float* __restrict__ s,   // [4,5504]
                                                     float* __restrict__ imp) {     // [4,5504]
  const int i = blockIdx.x;
  const int tid = threadIdx.x;
  const float4* row = (const float4*)(wu + (size_t)i * H_);
  float acc = 0.f;
#pragma unroll
  for (int t = 0; t < 2; ++t) {
    float4 v = row[tid + t * 256];
    acc += v.x * v.x + v.y * v.y + v.z * v.z + v.w * v.w;
  }
#pragma unroll
  for (int off = 32; off > 0; off >>= 1) acc += __shfl_down(acc, off, 64);
  __shared__ float wsum[4];
  if ((tid & 63) == 0) wsum[tid >> 6] = acc;
  __syncthreads();
  if (tid == 0) {
    const float rs = wsum[0] + wsum[1] + wsum[2] + wsum[3];
#pragma unroll
    for (int b = 0; b < 4; ++b) imp[b * I_ + i] = sqrtf(s[b * I_ + i] * rs);
  }
}

extern "C" void kernel_launch(void* const* d_in, const int* in_sizes, int n_in,
                              void* d_out, int out_size, void* d_ws, size_t ws_size,
                              hipStream_t stream) {
  const float* x = (const float*)d_in[0];   // [4,2048,2048]
  const float* wg = (const float*)d_in[1];  // [5504,2048]
  const float* wu = (const float*)d_in[2];  // [5504,2048]
  const float* wd = (const float*)d_in[3];  // [2048,5504]
  float* out = (float*)d_out;               // [4,2048,2048] then impacts [4,5504]
  float* imp = out + (size_t)M_ * H_;

  char* ws = (char*)d_ws;
  u16* xb = (u16*)(ws);                        // 33,554,432 B
  u16* wgb = (u16*)(ws + 33554432);            // 22,544,384 B
  u16* wub = (u16*)(ws + 56098816);            // 22,544,384 B
  u16* wdb = (u16*)(ws + 78643200);            // 22,544,384 B
  u16* interb = (u16*)(ws + 101187584);        // 90,177,536 B
  float* s = (float*)(ws + 191365120);         // 88,064 B  (total ~182.6 MiB)

  cvt_f32_bf16<<<16384, 256, 0, stream>>>(x, xb, (M_ * H_) / 4);
  cvt_f32_bf16<<<11008, 256, 0, stream>>>(wg, wgb, (I_ * H_) / 4);
  cvt_f32_bf16<<<11008, 256, 0, stream>>>(wu, wub, (I_ * H_) / 4);
  cvt_f32_bf16<<<11008, 256, 0, stream>>>(wd, wdb, (I_ * H_) / 4);
  hipMemsetAsync(s, 0, (size_t)B_ * I_ * sizeof(float), stream);

  gemm_gateup<<<(M_ / 128) * (I_ / 128), 256, 0, stream>>>(xb, wgb, wub, interb, s);
  gemm_down<<<(M_ / 128) * (H_ / 128), 256, 0, stream>>>(interb, wdb, out);
  rowsq_impacts<<<I_, 256, 0, stream>>>(wu, s, imp);
}